// Round 2
// baseline (195.205 us; speedup 1.0000x reference)
//
#include <hip/hip_runtime.h>
#include <hip/hip_cooperative_groups.h>
#include <math.h>

namespace cg = cooperative_groups;

#define NN 1024      // N
#define DIN 512      // D_IN
#define DD 128       // D

// ws layout (floats): x[1024*128], z[1024*128], u[256], a[1024], b[1024]
static constexpr long X_OFF = 0;
static constexpr long Z_OFF = X_OFF + (long)NN * DD;
static constexpr long U_OFF = Z_OFF + (long)NN * DD;
static constexpr long A_OFF = U_OFF + 256;
static constexpr long B_OFF = A_OFF + NN;

// One cooperative kernel, 256 blocks x 256 threads, 64 KB LDS (1-2 blocks/CU).
// Phase A: x = inputs @ W (4 rows/block, in-block split-K-2) ; u = W2 @ w3[:128]
// Phase B: z = adj @ x (same structure) ; a_i = relu(z_i).u[:128], b likewise
// Phase C: out[i,j] = sigmoid(a[i] + b[j] + z_i . (z_j * w3[128:]))  64x64 tiles
__global__ __launch_bounds__(256) void fused_encdec(
    const float* __restrict__ inputs, const float* __restrict__ adj,
    const float* __restrict__ W, const float* __restrict__ W2,
    const float* __restrict__ w3, float* __restrict__ out,
    float* __restrict__ x, float* __restrict__ z, float* __restrict__ u,
    float* __restrict__ a, float* __restrict__ b) {
  __shared__ float lds[16384];  // 64 KB, re-used per phase
  cg::grid_group grid = cg::this_grid();
  const int t = threadIdx.x;
  const int blk = blockIdx.x;

  // ---------------- Phase A: x = inputs @ W, rows 4*blk .. 4*blk+3
  {
    const float* src = inputs + (long)blk * 4 * DIN;  // 4 rows contiguous
#pragma unroll
    for (int j = 0; j < 2; ++j) {
      const int e = t * 8 + j * 4;  // 2048 floats staged
      *(float4*)&lds[e] = *(const float4*)&src[e];
    }
    __syncthreads();
    const int kh = t >> 7;         // in-block split-K half
    const int r  = (t >> 5) & 3;   // local row
    const int c4 = (t & 31) * 4;   // col group (float4)
    float a0 = 0.f, a1 = 0.f, a2 = 0.f, a3 = 0.f;
    const int k0 = kh * (DIN / 2);
#pragma unroll 4
    for (int k = k0; k < k0 + DIN / 2; ++k) {
      const float4 w = *(const float4*)&W[(long)k * DD + c4];
      const float av = lds[r * DIN + k];
      a0 += av * w.x; a1 += av * w.y; a2 += av * w.z; a3 += av * w.w;
    }
    float4 p; p.x = a0; p.y = a1; p.z = a2; p.w = a3;
    *(float4*)&lds[8192 + (kh * 4 + r) * DD + c4] = p;
    __syncthreads();
    if (kh == 0) {
      const float4 p0 = *(const float4*)&lds[8192 + r * DD + c4];
      const float4 p1 = *(const float4*)&lds[8192 + 512 + r * DD + c4];
      float4 v;
      v.x = p0.x + p1.x; v.y = p0.y + p1.y;
      v.z = p0.z + p1.z; v.w = p0.w + p1.w;
      *(float4*)&x[(long)(blk * 4 + r) * DD + c4] = v;
    }
    // u = W2 @ w3[:128] : blocks 0..7, lanes 0..31 each do one row
    if (blk < 8 && t < 32) {
      const int row = blk * 32 + t;
      float s = 0.f;
#pragma unroll 4
      for (int l = 0; l < DD; ++l) s += W2[(long)row * DD + l] * w3[l];
      u[row] = s;
    }
  }
  grid.sync();

  // ---------------- Phase B: z = adj @ x, rows 4*blk .. 4*blk+3 ; a, b
  {
    const float* src = adj + (long)blk * 4 * NN;  // 4 rows contiguous
#pragma unroll
    for (int j = 0; j < 4; ++j) {
      const int e = t * 16 + j * 4;  // 4096 floats staged
      *(float4*)&lds[e] = *(const float4*)&src[e];
    }
    __syncthreads();
    const int kh = t >> 7;
    const int r  = (t >> 5) & 3;
    const int c4 = (t & 31) * 4;
    float a0 = 0.f, a1 = 0.f, a2 = 0.f, a3 = 0.f;
    const int k0 = kh * (NN / 2);
#pragma unroll 4
    for (int k = k0; k < k0 + NN / 2; ++k) {
      const float4 xv = *(const float4*)&x[(long)k * DD + c4];
      const float av = lds[r * NN + k];
      a0 += av * xv.x; a1 += av * xv.y; a2 += av * xv.z; a3 += av * xv.w;
    }
    float4 p; p.x = a0; p.y = a1; p.z = a2; p.w = a3;
    *(float4*)&lds[8192 + (kh * 4 + r) * DD + c4] = p;
    __syncthreads();
    if (kh == 0) {
      const float4 p0 = *(const float4*)&lds[8192 + r * DD + c4];
      const float4 p1 = *(const float4*)&lds[8192 + 512 + r * DD + c4];
      float4 v;
      v.x = p0.x + p1.x; v.y = p0.y + p1.y;
      v.z = p0.z + p1.z; v.w = p0.w + p1.w;
      *(float4*)&z[(long)(blk * 4 + r) * DD + c4] = v;
      // a,b row-dot partial over this thread's 4 cols
      const float4 u0 = *(const float4*)&u[c4];
      const float4 u1 = *(const float4*)&u[DD + c4];
      const float rx = v.x > 0.f ? v.x : 0.f;
      const float ry = v.y > 0.f ? v.y : 0.f;
      const float rz = v.z > 0.f ? v.z : 0.f;
      const float rw = v.w > 0.f ? v.w : 0.f;
      float pa = rx * u0.x + ry * u0.y + rz * u0.z + rw * u0.w;
      float pb = rx * u1.x + ry * u1.y + rz * u1.z + rw * u1.w;
#pragma unroll
      for (int off = 16; off > 0; off >>= 1) {
        pa += __shfl_down(pa, off, 32);
        pb += __shfl_down(pb, off, 32);
      }
      if ((t & 31) == 0) {
        a[blk * 4 + r] = pa;
        b[blk * 4 + r] = pb;
      }
    }
  }
  grid.sync();

  // ---------------- Phase C: decode 64x64 tile per block
  {
    float* zl  = lds;         // rows i0.., XOR-swizzled
    float* zwl = lds + 8192;  // rows j0.. scaled by w3[128:]
    const int i0 = (blk >> 4) * 64;
    const int j0 = (blk & 15) * 64;
#pragma unroll
    for (int s = 0; s < 8; ++s) {
      const int q = s * 256 + t;      // 0..2047
      const int r = q >> 5;           // 0..63
      const int k4 = (q & 31) << 2;   // 0..124
      const int sw = r * DD + (k4 ^ ((r & 7) << 2));
      *(float4*)&zl[sw] = *(const float4*)&z[(long)(i0 + r) * DD + k4];
      float4 w = *(const float4*)&z[(long)(j0 + r) * DD + k4];
      const float4 c = *(const float4*)&w3[DD + k4];
      w.x *= c.x; w.y *= c.y; w.z *= c.z; w.w *= c.w;
      *(float4*)&zwl[sw] = w;
    }
    __syncthreads();

    const int tx = t & 15;
    const int ty = t >> 4;
    float acc[4][4] = {};
    for (int k4 = 0; k4 < DD; k4 += 4) {
      float4 ar[4], bc[4];
#pragma unroll
      for (int m = 0; m < 4; ++m) {
        const int R = ty + 16 * m;
        ar[m] = *(const float4*)&zl[R * DD + (k4 ^ ((R & 7) << 2))];
      }
#pragma unroll
      for (int m = 0; m < 4; ++m) {
        const int C = tx + 16 * m;
        bc[m] = *(const float4*)&zwl[C * DD + (k4 ^ ((C & 7) << 2))];
      }
#pragma unroll
      for (int mr = 0; mr < 4; ++mr)
#pragma unroll
        for (int mc = 0; mc < 4; ++mc)
          acc[mr][mc] += ar[mr].x * bc[mc].x + ar[mr].y * bc[mc].y +
                         ar[mr].z * bc[mc].z + ar[mr].w * bc[mc].w;
    }
#pragma unroll
    for (int mr = 0; mr < 4; ++mr) {
      const int i = i0 + ty + 16 * mr;
      const float ai = a[i];
#pragma unroll
      for (int mc = 0; mc < 4; ++mc) {
        const int j = j0 + tx + 16 * mc;
        const float s = ai + b[j] + acc[mr][mc];
        out[(long)i * NN + j] = 1.0f / (1.0f + __expf(-s));
      }
    }
  }
}

// ---------------------------------------------------------------------------
extern "C" void kernel_launch(void* const* d_in, const int* in_sizes, int n_in,
                              void* d_out, int out_size, void* d_ws, size_t ws_size,
                              hipStream_t stream) {
  (void)in_sizes; (void)n_in; (void)out_size; (void)ws_size;
  const float* inputs = (const float*)d_in[0];   // (1024, 512)
  const float* adj    = (const float*)d_in[1];   // (1024, 1024)
  const float* weight = (const float*)d_in[2];   // (512, 128)
  const float* W2     = (const float*)d_in[3];   // (256, 128)
  const float* w3     = (const float*)d_in[4];   // (256,)
  float* out = (float*)d_out;

  float* ws = (float*)d_ws;
  float* x = ws + X_OFF;
  float* z = ws + Z_OFF;
  float* u = ws + U_OFF;
  float* a = ws + A_OFF;
  float* b = ws + B_OFF;

  void* args[] = {(void*)&inputs, (void*)&adj, (void*)&weight, (void*)&W2,
                  (void*)&w3, (void*)&out, (void*)&x, (void*)&z, (void*)&u,
                  (void*)&a, (void*)&b};
  hipLaunchCooperativeKernel((const void*)fused_encdec, dim3(256), dim3(256),
                             args, 0, stream);
}

// Round 3
// 126.476 us; speedup vs baseline: 1.5434x; 1.5434x over previous
//
#include <hip/hip_runtime.h>
#include <math.h>

#define NN 1024      // N
#define DIN 512      // D_IN
#define DD 128       // D

// ws layout (floats): x[1024*128], z[1024*128], u[256], a[1024], b[1024]
static constexpr long X_OFF = 0;
static constexpr long Z_OFF = X_OFF + (long)NN * DD;
static constexpr long U_OFF = Z_OFF + (long)NN * DD;
static constexpr long A_OFF = U_OFF + 256;
static constexpr long B_OFF = A_OFF + NN;

// ---------------------------------------------------------------------------
// K1: x = inputs @ W  (1024x512 @ 512x128), plus u = W2 @ w3[:128].
// 128 blocks x 1024 threads (16 waves/CU = 4/SIMD on 128 CUs).
// Block handles 8 rows (staged in LDS, 16 KB); thread (rh=t>>7, c=t&127)
// computes one output with a 512-MAC dot: LDS broadcast * coalesced W column
// stream (W rows are L1-reused across the 8 row-groups).
__global__ __launch_bounds__(1024, 4) void k1_x_u(
    const float* __restrict__ inputs, const float* __restrict__ W,
    const float* __restrict__ W2, const float* __restrict__ w3,
    float* __restrict__ x, float* __restrict__ u) {
  __shared__ float arow[8 * DIN];  // 16 KB
  const int t = threadIdx.x;
  const int blk = blockIdx.x;  // rows 8*blk .. 8*blk+7

  ((float4*)arow)[t] = ((const float4*)(inputs + (long)blk * 8 * DIN))[t];
  __syncthreads();

  const int c = t & 127;
  const int rh = t >> 7;  // 0..7
  const float* wp = W + c;
  const float* ap = arow + rh * DIN;
  float acc = 0.f;
#pragma unroll 16
  for (int k = 0; k < DIN; ++k) acc += ap[k] * wp[(long)k * DD];
  x[(long)(blk * 8 + rh) * DD + c] = acc;

  // u on blocks 0..7: 32 rows of W2 each, 8 lanes per row.
  if (blk < 8 && t < 256) {
    const int row = blk * 32 + (t >> 3);
    const int l8 = t & 7;
    float s = 0.f;
#pragma unroll
    for (int i = 0; i < 16; ++i) {
      const int l = l8 + 8 * i;
      s += W2[(long)row * DD + l] * w3[l];
    }
#pragma unroll
    for (int off = 4; off > 0; off >>= 1) s += __shfl_down(s, off, 8);
    if (l8 == 0) u[row] = s;
  }
}

// ---------------------------------------------------------------------------
// K2: z = adj @ x (1024x1024 @ 1024x128); fused a_i = relu(z_i).u[:128],
// b_i = relu(z_i).u[128:]. Same 128x1024 shape; 8 adj rows in LDS (32 KB);
// thread (rh,c) computes z[row][c] via 1024-MAC dot (x column stream from
// L1/L2, coalesced over lanes). Row-group's 128 threads (2 waves) then
// shuffle+LDS-reduce relu(z)*u into a,b.
__global__ __launch_bounds__(1024, 4) void k2_z_ab(
    const float* __restrict__ adj, const float* __restrict__ x,
    const float* __restrict__ u, float* __restrict__ z,
    float* __restrict__ a, float* __restrict__ b) {
  __shared__ float arow[8 * NN];  // 32 KB
  __shared__ float red[16][2];
  const int t = threadIdx.x;
  const int blk = blockIdx.x;  // rows 8*blk .. 8*blk+7

  const float4* src = (const float4*)(adj + (long)blk * 8 * NN);
#pragma unroll
  for (int s = 0; s < 2; ++s) ((float4*)arow)[s * 1024 + t] = src[s * 1024 + t];
  __syncthreads();

  const int c = t & 127;
  const int rh = t >> 7;  // 0..7
  const float* xp = x + c;
  const float* ap = arow + rh * NN;
  float acc = 0.f;
#pragma unroll 16
  for (int k = 0; k < NN; ++k) acc += ap[k] * xp[(long)k * DD];
  const int row = blk * 8 + rh;
  z[(long)row * DD + c] = acc;

  const float r = acc > 0.f ? acc : 0.f;
  float pa = r * u[c];
  float pb = r * u[DD + c];
#pragma unroll
  for (int off = 32; off > 0; off >>= 1) {
    pa += __shfl_down(pa, off);
    pb += __shfl_down(pb, off);
  }
  const int w = t >> 6;  // wave id 0..15; waves 2*rh, 2*rh+1 belong to row rh
  if ((t & 63) == 0) { red[w][0] = pa; red[w][1] = pb; }
  __syncthreads();
  if (t < 8) {
    a[blk * 8 + t] = red[2 * t][0] + red[2 * t + 1][0];
    b[blk * 8 + t] = red[2 * t][1] + red[2 * t + 1][1];
  }
}

// ---------------------------------------------------------------------------
// K3: decode tile (verified in R1): out[i,j] = sigmoid(a[i]+b[j]+
// z_i.(z_j*w3[128:])). 64x64 tile per block, 256 threads, 4x4 per thread,
// XOR-swizzled LDS (conflict-free b128 column reads).
__global__ __launch_bounds__(256) void decode_tile(
    const float* __restrict__ z, const float* __restrict__ w3,
    const float* __restrict__ a, const float* __restrict__ b,
    float* __restrict__ out) {
  __shared__ float zl[64 * DD];
  __shared__ float zwl[64 * DD];
  const int t = threadIdx.x;
  const int i0 = blockIdx.y * 64;
  const int j0 = blockIdx.x * 64;

#pragma unroll
  for (int s = 0; s < 8; ++s) {
    const int q = s * 256 + t;
    const int r = q >> 5;
    const int k4 = (q & 31) << 2;
    const int sw = r * DD + (k4 ^ ((r & 7) << 2));
    *(float4*)&zl[sw] = *(const float4*)&z[(long)(i0 + r) * DD + k4];
    float4 w = *(const float4*)&z[(long)(j0 + r) * DD + k4];
    const float4 c = *(const float4*)&w3[DD + k4];
    w.x *= c.x; w.y *= c.y; w.z *= c.z; w.w *= c.w;
    *(float4*)&zwl[sw] = w;
  }
  __syncthreads();

  const int tx = t & 15;
  const int ty = t >> 4;
  float acc[4][4] = {};
  for (int k4 = 0; k4 < DD; k4 += 4) {
    float4 ar[4], bc[4];
#pragma unroll
    for (int m = 0; m < 4; ++m) {
      const int R = ty + 16 * m;
      ar[m] = *(const float4*)&zl[R * DD + (k4 ^ ((R & 7) << 2))];
    }
#pragma unroll
    for (int m = 0; m < 4; ++m) {
      const int C = tx + 16 * m;
      bc[m] = *(const float4*)&zwl[C * DD + (k4 ^ ((C & 7) << 2))];
    }
#pragma unroll
    for (int mr = 0; mr < 4; ++mr)
#pragma unroll
      for (int mc = 0; mc < 4; ++mc)
        acc[mr][mc] += ar[mr].x * bc[mc].x + ar[mr].y * bc[mc].y +
                       ar[mr].z * bc[mc].z + ar[mr].w * bc[mc].w;
  }

#pragma unroll
  for (int mr = 0; mr < 4; ++mr) {
    const int i = i0 + ty + 16 * mr;
    const float ai = a[i];
#pragma unroll
    for (int mc = 0; mc < 4; ++mc) {
      const int j = j0 + tx + 16 * mc;
      const float s = ai + b[j] + acc[mr][mc];
      out[(long)i * NN + j] = 1.0f / (1.0f + __expf(-s));
    }
  }
}

// ---------------------------------------------------------------------------
extern "C" void kernel_launch(void* const* d_in, const int* in_sizes, int n_in,
                              void* d_out, int out_size, void* d_ws, size_t ws_size,
                              hipStream_t stream) {
  (void)in_sizes; (void)n_in; (void)out_size; (void)ws_size;
  const float* inputs = (const float*)d_in[0];   // (1024, 512)
  const float* adj    = (const float*)d_in[1];   // (1024, 1024)
  const float* weight = (const float*)d_in[2];   // (512, 128)
  const float* W2     = (const float*)d_in[3];   // (256, 128)
  const float* w3     = (const float*)d_in[4];   // (256,)
  float* out = (float*)d_out;

  float* ws = (float*)d_ws;
  float* x = ws + X_OFF;
  float* z = ws + Z_OFF;
  float* u = ws + U_OFF;
  float* a = ws + A_OFF;
  float* b = ws + B_OFF;

  k1_x_u<<<128, 1024, 0, stream>>>(inputs, weight, W2, w3, x, u);
  k2_z_ab<<<128, 1024, 0, stream>>>(adj, x, u, z, a, b);
  decode_tile<<<dim3(16, 16), 256, 0, stream>>>(z, w3, a, b, out);
}

// Round 4
// 110.123 us; speedup vs baseline: 1.7726x; 1.1485x over previous
//
#include <hip/hip_runtime.h>
#include <math.h>

#define NN 1024      // N
#define DIN 512      // D_IN
#define DD 128       // D

static constexpr long S = (long)NN * DD;       // 131072 floats per matrix
// ws layout (floats)
static constexpr long XP_OFF = 0;              // 16 x-partials
static constexpr long ZP_OFF = XP_OFF + 16 * S;
static constexpr long X_OFF  = ZP_OFF + 32 * S;  // 32 z-partials
static constexpr long Z_OFF  = X_OFF + S;
static constexpr long U_OFF  = Z_OFF + S;
static constexpr long A_OFF  = U_OFF + 256;
static constexpr long B_OFF  = A_OFF + NN;

// ---------------------------------------------------------------------------
// Split-K fp32 GEMM partial: Cp[split] (32 rows x 128 cols per block).
// grid.x = 32 row-blocks, grid.y = K/Kc splits; 256 threads, no LDS.
// Thread (tx=t&31, ty=t>>5): rows ty+8*mr, cols tx+32*mc — 16 independent
// accumulators (ILP) with Kc/4 chain segments of 4 FMAs each.
__global__ __launch_bounds__(256) void gemm_part(
    const float* __restrict__ A, const float* __restrict__ B,
    float* __restrict__ Cp, int K, int Kc) {
  const int t = threadIdx.x;
  const int tx = t & 31;
  const int ty = t >> 5;
  const int row0 = blockIdx.x * 32;
  const int k0 = blockIdx.y * Kc;

  float acc[4][4] = {};

  for (int k = k0; k < k0 + Kc; k += 4) {
    float bv[4][4];
#pragma unroll
    for (int kk = 0; kk < 4; ++kk) {
      const float* Brow = &B[(long)(k + kk) * DD + tx];
#pragma unroll
      for (int mc = 0; mc < 4; ++mc) bv[kk][mc] = Brow[32 * mc];
    }
#pragma unroll
    for (int mr = 0; mr < 4; ++mr) {
      const int r = row0 + ty + 8 * mr;
      const float4 av = *(const float4*)&A[(long)r * K + k];
      const float ar[4] = {av.x, av.y, av.z, av.w};
#pragma unroll
      for (int kk = 0; kk < 4; ++kk)
#pragma unroll
        for (int mc = 0; mc < 4; ++mc) acc[mr][mc] += ar[kk] * bv[kk][mc];
    }
  }

  float* Cs = Cp + (long)blockIdx.y * S;
#pragma unroll
  for (int mr = 0; mr < 4; ++mr) {
    const int r = row0 + ty + 8 * mr;
#pragma unroll
    for (int mc = 0; mc < 4; ++mc)
      Cs[(long)r * DD + tx + 32 * mc] = acc[mr][mc];
  }
}

// ---------------------------------------------------------------------------
// Reduce 16 x-partials -> x ; block 0 also computes u = W2 @ w3[:128].
__global__ __launch_bounds__(256) void reduce_x_u(
    const float* __restrict__ xp, float* __restrict__ x,
    const float* __restrict__ W2, const float* __restrict__ w3,
    float* __restrict__ u) {
  const long i = (long)blockIdx.x * 256 + threadIdx.x;  // 0..131071
  float s = 0.f;
#pragma unroll
  for (int p = 0; p < 16; ++p) s += xp[p * S + i];
  x[i] = s;

  if (blockIdx.x == 0) {
    const int kq = threadIdx.x;  // 0..255
    float uu = 0.f;
#pragma unroll 4
    for (int l = 0; l < DD; ++l) uu += W2[(long)kq * DD + l] * w3[l];
    u[kq] = uu;
  }
}

// ---------------------------------------------------------------------------
// Reduce 32 z-partials -> z ; fused a_i/b_i. grid = 1024 rows, block = 128.
__global__ __launch_bounds__(128) void finalize_z(
    const float* __restrict__ zp, float* __restrict__ z,
    const float* __restrict__ u, float* __restrict__ a, float* __restrict__ b) {
  __shared__ float red[2][2];
  const int i = blockIdx.x;
  const int c = threadIdx.x;  // 0..127 = column
  float s = 0.f;
#pragma unroll
  for (int p = 0; p < 32; ++p) s += zp[p * S + (long)i * DD + c];
  z[(long)i * DD + c] = s;

  const float r = s > 0.f ? s : 0.f;
  float pa = r * u[c];
  float pb = r * u[DD + c];
#pragma unroll
  for (int off = 32; off > 0; off >>= 1) {
    pa += __shfl_down(pa, off);
    pb += __shfl_down(pb, off);
  }
  const int w = c >> 6;
  if ((c & 63) == 0) { red[w][0] = pa; red[w][1] = pb; }
  __syncthreads();
  if (c == 0) {
    a[i] = red[0][0] + red[1][0];
    b[i] = red[0][1] + red[1][1];
  }
}

// ---------------------------------------------------------------------------
// Decode: out[i,j] = sigmoid(a[i] + b[j] + z_i . (z_j * w3[128:])).
// 64x64 tile, 512 threads (8 waves -> 2/SIMD), 2x4 outputs/thread.
// XOR-swizzled LDS: column b128 reads land 2 lanes/bank (free).
__global__ __launch_bounds__(512) void decode_tile(
    const float* __restrict__ z, const float* __restrict__ w3,
    const float* __restrict__ a, const float* __restrict__ b,
    float* __restrict__ out) {
  __shared__ float zl[64 * DD];   // rows i0..
  __shared__ float zwl[64 * DD];  // rows j0.. scaled by w3[128:]
  const int t = threadIdx.x;
  const int i0 = blockIdx.y * 64;
  const int j0 = blockIdx.x * 64;

#pragma unroll
  for (int s = 0; s < 4; ++s) {
    const int q = s * 512 + t;      // 0..2047
    const int r = q >> 5;           // 0..63
    const int k4 = (q & 31) << 2;   // 0..124
    const int sw = r * DD + (k4 ^ ((r & 7) << 2));
    *(float4*)&zl[sw] = *(const float4*)&z[(long)(i0 + r) * DD + k4];
    float4 w = *(const float4*)&z[(long)(j0 + r) * DD + k4];
    const float4 c = *(const float4*)&w3[DD + k4];
    w.x *= c.x; w.y *= c.y; w.z *= c.z; w.w *= c.w;
    *(float4*)&zwl[sw] = w;
  }
  __syncthreads();

  const int tx = t & 15;   // col group
  const int ty = t >> 4;   // 0..31 row
  float acc[2][4] = {};
  for (int k4 = 0; k4 < DD; k4 += 4) {
    float4 ar[2], bc[4];
#pragma unroll
    for (int m = 0; m < 2; ++m) {
      const int R = ty + 32 * m;
      ar[m] = *(const float4*)&zl[R * DD + (k4 ^ ((R & 7) << 2))];
    }
#pragma unroll
    for (int m = 0; m < 4; ++m) {
      const int C = tx + 16 * m;
      bc[m] = *(const float4*)&zwl[C * DD + (k4 ^ ((C & 7) << 2))];
    }
#pragma unroll
    for (int mr = 0; mr < 2; ++mr)
#pragma unroll
      for (int mc = 0; mc < 4; ++mc)
        acc[mr][mc] += ar[mr].x * bc[mc].x + ar[mr].y * bc[mc].y +
                       ar[mr].z * bc[mc].z + ar[mr].w * bc[mc].w;
  }

#pragma unroll
  for (int mr = 0; mr < 2; ++mr) {
    const int i = i0 + ty + 32 * mr;
    const float ai = a[i];
#pragma unroll
    for (int mc = 0; mc < 4; ++mc) {
      const int j = j0 + tx + 16 * mc;
      const float s = ai + b[j] + acc[mr][mc];
      out[(long)i * NN + j] = 1.0f / (1.0f + __expf(-s));
    }
  }
}

// ---------------------------------------------------------------------------
extern "C" void kernel_launch(void* const* d_in, const int* in_sizes, int n_in,
                              void* d_out, int out_size, void* d_ws, size_t ws_size,
                              hipStream_t stream) {
  (void)in_sizes; (void)n_in; (void)out_size; (void)ws_size;
  const float* inputs = (const float*)d_in[0];   // (1024, 512)
  const float* adj    = (const float*)d_in[1];   // (1024, 1024)
  const float* weight = (const float*)d_in[2];   // (512, 128)
  const float* W2     = (const float*)d_in[3];   // (256, 128)
  const float* w3     = (const float*)d_in[4];   // (256,)
  float* out = (float*)d_out;

  float* ws = (float*)d_ws;
  float* xp = ws + XP_OFF;
  float* zp = ws + ZP_OFF;
  float* x  = ws + X_OFF;
  float* z  = ws + Z_OFF;
  float* u  = ws + U_OFF;
  float* a  = ws + A_OFF;
  float* b  = ws + B_OFF;

  // 1) x partials: split-K 16 -> 512 blocks (2/CU)
  gemm_part<<<dim3(32, 16), 256, 0, stream>>>(inputs, weight, xp, DIN, DIN / 16);
  // 2) reduce x (+u)
  reduce_x_u<<<512, 256, 0, stream>>>(xp, x, W2, w3, u);
  // 3) z partials: split-K 32 -> 1024 blocks (4/CU)
  gemm_part<<<dim3(32, 32), 256, 0, stream>>>(adj, x, zp, NN, NN / 32);
  // 4) reduce z + a,b
  finalize_z<<<1024, 128, 0, stream>>>(zp, z, u, a, b);
  // 5) decode
  decode_tile<<<dim3(16, 16), 512, 0, stream>>>(z, w3, a, b, out);
}